// Round 7
// baseline (58.180 us; speedup 1.0000x reference)
//
#include <hip/hip_runtime.h>
#include <hip/hip_bf16.h>

// ---- problem constants ----
#define BATCH 16
#define CIN   12
#define HIMG  512
#define WIMG  512
#define OCH   768
#define KDIM  256            // 16*16 patch
#define HW    (HIMG*WIMG)    // 262144
#define NPATCH 1024          // 32*32 patches per batch

#define MEAN_BLOCKS 4096     // BATCH*HW/4/256
#define PACK_BLOCKS 96       // OCH*KDIM/8/256

typedef __attribute__((ext_vector_type(8))) short short8;   // 8 bf16 = 4 VGPRs
typedef __attribute__((ext_vector_type(4))) float f32x4;

// ---------------------------------------------------------------------------
// Kernel A (merged): channel-mean (blocks 0..4095) + weight pack (4096..4191).
// mean: xm[b][h][w] = mean_c x[b][c][h][w], f32 -> bf16 (R1-validated body).
// pack: w f32 -> bf16 in MFMA fragment-lane order:
//   packed[u][0..7], u = (ot*8 + kk)*64 + lane holds
//   w[ot*16 + (lane&15)][kk*32 + (lane>>4)*8 + j], j=0..7.
// ---------------------------------------------------------------------------
__global__ __launch_bounds__(256) void mean_pack_kernel(
        const float* __restrict__ x, __hip_bfloat16* __restrict__ xm,
        const float* __restrict__ w, short8* __restrict__ wbp) {
    const int bid = blockIdx.x;
    if (bid < MEAN_BLOCKS) {
        int idx = bid * 256 + threadIdx.x;              // float4 index
        int b = idx >> 16;                              // 65536 float4 per image
        int pos = (idx & 65535) << 2;
        const float* px = x + (size_t)b * CIN * HW + pos;
        float sx = 0.f, sy = 0.f, sz = 0.f, sw = 0.f;
        #pragma unroll
        for (int c = 0; c < CIN; ++c) {
            f32x4 v = *reinterpret_cast<const f32x4*>(px + (size_t)c * HW);
            sx += v.x; sy += v.y; sz += v.z; sw += v.w;
        }
        const float inv = 1.0f / 12.0f;
        union { ushort4 u4; __hip_bfloat16 h[4]; } o;
        o.h[0] = __float2bfloat16(sx * inv);
        o.h[1] = __float2bfloat16(sy * inv);
        o.h[2] = __float2bfloat16(sz * inv);
        o.h[3] = __float2bfloat16(sw * inv);
        *reinterpret_cast<ushort4*>(xm + (size_t)idx * 4) = o.u4;
    } else {
        int u = (bid - MEAN_BLOCKS) * 256 + threadIdx.x;   // 0..24575
        int lane = u & 63;
        int kk   = (u >> 6) & 7;
        int ot   = u >> 9;                                 // 0..47
        int o = ot * 16 + (lane & 15);
        int k = kk * 32 + (lane >> 4) * 8;
        const float* src = w + (size_t)o * KDIM + k;
        f32x4 v0 = *reinterpret_cast<const f32x4*>(src);
        f32x4 v1 = *reinterpret_cast<const f32x4*>(src + 4);
        union { short8 s; __hip_bfloat16 h[8]; } t;
        t.h[0] = __float2bfloat16(v0.x);
        t.h[1] = __float2bfloat16(v0.y);
        t.h[2] = __float2bfloat16(v0.z);
        t.h[3] = __float2bfloat16(v0.w);
        t.h[4] = __float2bfloat16(v1.x);
        t.h[5] = __float2bfloat16(v1.y);
        t.h[6] = __float2bfloat16(v1.z);
        t.h[7] = __float2bfloat16(v1.w);
        wbp[u] = t.s;
    }
}

// ---------------------------------------------------------------------------
// Kernel B: patch-embedding GEMM, 1024 blocks x 256 threads (4 waves).
// Block = (batch b, stripe is, o-half oh): 32 patches x 384 o-channels.
// Wave wv owns o-range oh*384 + wv*96 .. +96  x 32 patches = 6x2 fragments
// of 16x16x32 bf16 MFMA, K = 256 in 8 steps.
// Phase 1: copy the 16 KB bf16 stripe of xm into LDS tile Bl[m=j][k=r*16+s].
// Phase 2: A-fragments stream from packed weights (L2-resident, coalesced
//   1 KiB wave loads), B-fragments from LDS.
// Epilogue: NON-TEMPORAL stores (no L3 allocation -> x stays L3-resident
//   for the next replay's mean kernel).
// ---------------------------------------------------------------------------
#define LDB 264   // 256 + 8 pad

__global__ __launch_bounds__(256, 4) void gemm_kernel(
        const short8* __restrict__ wbp,          // packed weights
        const __hip_bfloat16* __restrict__ xm,   // [B][H][W] mean image
        const float* __restrict__ bias,
        float* __restrict__ out) {               // [B][O][32][32]
    __shared__ short Bl[32][LDB];

    const int tid = threadIdx.x;
    const int b  = blockIdx.x >> 6;
    const int is = (blockIdx.x >> 1) & 31;   // stripe / patch-row index
    const int oh = blockIdx.x & 1;           // o-half

    // ---- phase 1: 16 rows x 512 cols bf16 -> LDS (4 short8 per thread) ----
    {
        const int r   = tid >> 4;            // 0..15
        const int seg = tid & 15;            // 0..15, 32 shorts each
        const short* src = reinterpret_cast<const short*>(
            xm + (size_t)b * HW + (size_t)(is * 16 + r) * WIMG + seg * 32);
        #pragma unroll
        for (int q = 0; q < 4; ++q) {
            // col c = seg*32 + q*8 -> patch j = seg*2 + (q>>1), s = (q&1)*8
            *reinterpret_cast<short8*>(&Bl[seg * 2 + (q >> 1)][r * 16 + (q & 1) * 8]) =
                *reinterpret_cast<const short8*>(src + q * 8);
        }
    }
    __syncthreads();

    // ---- phase 2: MFMA ----
    const int lane = tid & 63;
    const int wv   = tid >> 6;           // 0..3
    const int lrow = lane & 15;
    const int lg   = lane >> 4;

    f32x4 acc[6][2] = {};
    // global o-tile base: (oh*384 + wv*96)/16 = oh*24 + wv*6 sixteens
    const short8* wp = wbp + (size_t)(oh * 24 + wv * 6) * 8 * 64 + lane;

    #pragma unroll
    for (int kk = 0; kk < 8; ++kk) {
        short8 af[6], bf[2];
        #pragma unroll
        for (int fo = 0; fo < 6; ++fo)
            af[fo] = wp[(size_t)(fo * 8 + kk) * 64];
        #pragma unroll
        for (int fm = 0; fm < 2; ++fm)
            bf[fm] = *reinterpret_cast<const short8*>(&Bl[fm * 16 + lrow][kk * 32 + lg * 8]);
        #pragma unroll
        for (int fo = 0; fo < 6; ++fo)
            #pragma unroll
            for (int fm = 0; fm < 2; ++fm)
                acc[fo][fm] = __builtin_amdgcn_mfma_f32_16x16x32_bf16(af[fo], bf[fm], acc[fo][fm], 0, 0, 0);
    }

    // ---- epilogue: D row = o ((lane>>4)*4 + reg), col = m (lane&15) ----
    const int p0 = is * 32;
    float* ob = out + (size_t)b * OCH * NPATCH + p0;
    #pragma unroll
    for (int fo = 0; fo < 6; ++fo) {
        const int obase = oh * 384 + wv * 96 + fo * 16 + lg * 4;
        #pragma unroll
        for (int r = 0; r < 4; ++r) {
            const int o = obase + r;
            const float bv = bias[o];
            float* orow = ob + (size_t)o * NPATCH;
            #pragma unroll
            for (int fm = 0; fm < 2; ++fm)
                __builtin_nontemporal_store(acc[fo][fm][r] + bv,
                                            orow + fm * 16 + lrow);
        }
    }
}

// ---------------------------------------------------------------------------
extern "C" void kernel_launch(void* const* d_in, const int* in_sizes, int n_in,
                              void* d_out, int out_size, void* d_ws, size_t ws_size,
                              hipStream_t stream) {
    const float* x    = (const float*)d_in[0];
    const float* w    = (const float*)d_in[1];
    const float* bias = (const float*)d_in[2];
    float* out = (float*)d_out;

    __hip_bfloat16* xm = (__hip_bfloat16*)d_ws;                                   // 8 MiB
    short8* wbp = (short8*)((char*)d_ws + (size_t)BATCH * HW * 2);                // 384 KiB

    mean_pack_kernel<<<MEAN_BLOCKS + PACK_BLOCKS, 256, 0, stream>>>(x, xm, w, wbp);
    gemm_kernel<<<BATCH * 32 * 2, 256, 0, stream>>>(wbp, xm, bias, out);
}

// Round 8
// 51.140 us; speedup vs baseline: 1.1377x; 1.1377x over previous
//
#include <hip/hip_runtime.h>
#include <hip/hip_bf16.h>

// ---- problem constants ----
#define BATCH 16
#define CIN   12
#define HIMG  512
#define WIMG  512
#define OCH   768
#define KDIM  256            // 16*16 patch
#define HW    (HIMG*WIMG)    // 262144
#define NPATCH 1024          // 32*32 patches per batch

#define MEAN_BLOCKS 4096     // BATCH*HW/4/256
#define PACK_BLOCKS 96       // OCH*KDIM/8/256

typedef __attribute__((ext_vector_type(8))) short short8;   // 8 bf16 = 4 VGPRs
typedef __attribute__((ext_vector_type(4))) float f32x4;

// ---------------------------------------------------------------------------
// Kernel A (merged): channel-mean (blocks 0..4095) + weight pack (4096..4191).
// mean: xm[b][h][w] = mean_c x[b][c][h][w], f32 -> bf16 (R1-validated body).
// pack: w f32 -> bf16 in MFMA fragment-lane order:
//   packed[u][0..7], u = (ot*8 + kk)*64 + lane holds
//   w[ot*16 + (lane&15)][kk*32 + (lane>>4)*8 + j], j=0..7.
// ---------------------------------------------------------------------------
__global__ __launch_bounds__(256) void mean_pack_kernel(
        const float* __restrict__ x, __hip_bfloat16* __restrict__ xm,
        const float* __restrict__ w, short8* __restrict__ wbp) {
    const int bid = blockIdx.x;
    if (bid < MEAN_BLOCKS) {
        int idx = bid * 256 + threadIdx.x;              // float4 index
        int b = idx >> 16;                              // 65536 float4 per image
        int pos = (idx & 65535) << 2;
        const float* px = x + (size_t)b * CIN * HW + pos;
        float sx = 0.f, sy = 0.f, sz = 0.f, sw = 0.f;
        #pragma unroll
        for (int c = 0; c < CIN; ++c) {
            f32x4 v = *reinterpret_cast<const f32x4*>(px + (size_t)c * HW);
            sx += v.x; sy += v.y; sz += v.z; sw += v.w;
        }
        const float inv = 1.0f / 12.0f;
        union { ushort4 u4; __hip_bfloat16 h[4]; } o;
        o.h[0] = __float2bfloat16(sx * inv);
        o.h[1] = __float2bfloat16(sy * inv);
        o.h[2] = __float2bfloat16(sz * inv);
        o.h[3] = __float2bfloat16(sw * inv);
        *reinterpret_cast<ushort4*>(xm + (size_t)idx * 4) = o.u4;
    } else {
        int u = (bid - MEAN_BLOCKS) * 256 + threadIdx.x;   // 0..24575
        int lane = u & 63;
        int kk   = (u >> 6) & 7;
        int ot   = u >> 9;                                 // 0..47
        int o = ot * 16 + (lane & 15);
        int k = kk * 32 + (lane >> 4) * 8;
        const float* src = w + (size_t)o * KDIM + k;
        f32x4 v0 = *reinterpret_cast<const f32x4*>(src);
        f32x4 v1 = *reinterpret_cast<const f32x4*>(src + 4);
        union { short8 s; __hip_bfloat16 h[8]; } t;
        t.h[0] = __float2bfloat16(v0.x);
        t.h[1] = __float2bfloat16(v0.y);
        t.h[2] = __float2bfloat16(v0.z);
        t.h[3] = __float2bfloat16(v0.w);
        t.h[4] = __float2bfloat16(v1.x);
        t.h[5] = __float2bfloat16(v1.y);
        t.h[6] = __float2bfloat16(v1.z);
        t.h[7] = __float2bfloat16(v1.w);
        wbp[u] = t.s;
    }
}

// ---------------------------------------------------------------------------
// Kernel B: patch-embedding GEMM, 512 blocks x 512 threads (8 waves).
// Block = (batch b, stripe-PAIR sp, o-half oh): 64 patches x 384 o-channels.
//   -> weight re-read per block halves vs the R6 tiling (192 KB/block,
//      98 MB total L2 traffic), same 2 blocks/CU residency.
// Wave wv owns o-range oh*384 + wv*48 .. +48 (3 frags) x 64 patches (4 frags)
// of 16x16x32 bf16 MFMA, K = 256 in 8 steps.  acc[3][4] = 48 VGPR.
// Phase 1: copy 32 rows x 512 cols of xm (32 KB) into LDS tile
//   Bl[m = si*32+j][k = r*16+s].
// Phase 2: A-fragments stream from packed weights (L2-resident, coalesced
//   1 KiB wave loads), B-fragments from LDS.
// Epilogue: out[b][o][sp*64 + mm] — 64-contiguous coalesced f32 stores.
// ---------------------------------------------------------------------------
#define LDB 264   // 256 + 8 pad

__global__ __launch_bounds__(512, 4) void gemm_kernel(
        const short8* __restrict__ wbp,          // packed weights
        const __hip_bfloat16* __restrict__ xm,   // [B][H][W] mean image
        const float* __restrict__ bias,
        float* __restrict__ out) {               // [B][O][32][32]
    __shared__ short Bl[64][LDB];

    const int tid = threadIdx.x;
    const int b  = blockIdx.x >> 5;
    const int sp = (blockIdx.x >> 1) & 15;   // stripe pair (2 patch rows)
    const int oh = blockIdx.x & 1;           // o-half

    // ---- phase 1: 32 image rows x 512 cols bf16 -> LDS (4 short8/thread) ----
    {
        const int r   = tid >> 4;            // 0..31 image row within pair
        const int seg = tid & 15;            // 0..15, 32 shorts (64 B) each
        const int si  = r >> 4;              // stripe within pair
        const int r16 = r & 15;              // k-row within patch
        const short* src = reinterpret_cast<const short*>(
            xm + (size_t)b * HW + (size_t)(sp * 32 + r) * WIMG + seg * 32);
        #pragma unroll
        for (int q = 0; q < 4; ++q) {
            // col = seg*32 + q*8 -> patch j = seg*2 + (q>>1), s0 = (q&1)*8
            *reinterpret_cast<short8*>(
                &Bl[si * 32 + seg * 2 + (q >> 1)][r16 * 16 + (q & 1) * 8]) =
                *reinterpret_cast<const short8*>(src + q * 8);
        }
    }
    __syncthreads();

    // ---- phase 2: MFMA ----
    const int lane = tid & 63;
    const int wv   = tid >> 6;           // 0..7
    const int lrow = lane & 15;
    const int lg   = lane >> 4;

    f32x4 acc[3][4] = {};
    // global 16-row weight tile index: base_ot = (oh*384 + wv*48)/16
    const short8* wp = wbp + (size_t)(oh * 24 + wv * 3) * 8 * 64 + lane;

    #pragma unroll
    for (int kk = 0; kk < 8; ++kk) {
        short8 af[3], bf[4];
        #pragma unroll
        for (int fo = 0; fo < 3; ++fo)
            af[fo] = wp[(size_t)(fo * 8 + kk) * 64];
        #pragma unroll
        for (int fm = 0; fm < 4; ++fm)
            bf[fm] = *reinterpret_cast<const short8*>(&Bl[fm * 16 + lrow][kk * 32 + lg * 8]);
        #pragma unroll
        for (int fo = 0; fo < 3; ++fo)
            #pragma unroll
            for (int fm = 0; fm < 4; ++fm)
                acc[fo][fm] = __builtin_amdgcn_mfma_f32_16x16x32_bf16(af[fo], bf[fm], acc[fo][fm], 0, 0, 0);
    }

    // ---- epilogue: D row = o ((lane>>4)*4 + reg), col = m (lane&15) ----
    float* ob = out + (size_t)b * OCH * NPATCH + sp * 64;
    #pragma unroll
    for (int fo = 0; fo < 3; ++fo) {
        const int obase = oh * 384 + wv * 48 + fo * 16 + lg * 4;
        #pragma unroll
        for (int r = 0; r < 4; ++r) {
            const int o = obase + r;
            const float bv = bias[o];
            float* orow = ob + (size_t)o * NPATCH;
            #pragma unroll
            for (int fm = 0; fm < 4; ++fm)
                orow[fm * 16 + lrow] = acc[fo][fm][r] + bv;
        }
    }
}

// ---------------------------------------------------------------------------
extern "C" void kernel_launch(void* const* d_in, const int* in_sizes, int n_in,
                              void* d_out, int out_size, void* d_ws, size_t ws_size,
                              hipStream_t stream) {
    const float* x    = (const float*)d_in[0];
    const float* w    = (const float*)d_in[1];
    const float* bias = (const float*)d_in[2];
    float* out = (float*)d_out;

    __hip_bfloat16* xm = (__hip_bfloat16*)d_ws;                                   // 8 MiB
    short8* wbp = (short8*)((char*)d_ws + (size_t)BATCH * HW * 2);                // 384 KiB

    mean_pack_kernel<<<MEAN_BLOCKS + PACK_BLOCKS, 256, 0, stream>>>(x, xm, w, wbp);
    gemm_kernel<<<512, 512, 0, stream>>>(wbp, xm, bias, out);
}